// Round 11
// baseline (175.592 us; speedup 1.0000x reference)
//
#include <hip/hip_runtime.h>
#include <hip/hip_bf16.h>
#include <math.h>

typedef __attribute__((ext_vector_type(8))) short short8;
typedef __attribute__((ext_vector_type(4))) float f32x4;
typedef __attribute__((ext_vector_type(4))) short short4v;
typedef __attribute__((ext_vector_type(2))) int int2v;

static __device__ __forceinline__ short f2bf(float f) {
    __hip_bfloat16 h = __float2bfloat16(f);
    return *reinterpret_cast<short*>(&h);
}
static __device__ __forceinline__ void store_out(float* p, float v) { *p = v; }
static __device__ __forceinline__ void store_out(short* p, float v) { *p = f2bf(v); }

#define GLL16(g, l) __builtin_amdgcn_global_load_lds( \
    (const __attribute__((address_space(1))) void*)(g), \
    (__attribute__((address_space(3))) void*)(l), 16, 0, 0)

#if __has_builtin(__builtin_amdgcn_exp2f)
#define EXP2(x) __builtin_amdgcn_exp2f(x)
#else
#define EXP2(x) exp2f(x)
#endif

// pack two f32 -> packed bf16 pair (low = a, high = b)
#if __has_builtin(__builtin_amdgcn_cvt_pk_bf16_f32)
typedef __attribute__((ext_vector_type(2))) __bf16 bf16x2;
static __device__ __forceinline__ int pack2bf(float a, float b) {
    bf16x2 r = __builtin_amdgcn_cvt_pk_bf16_f32(a, b);
    return __builtin_bit_cast(int, r);
}
#else
static __device__ __forceinline__ int pack2bf(float a, float b) {
    unsigned ua = __builtin_bit_cast(unsigned, a) + 0x8000u;
    unsigned ub = __builtin_bit_cast(unsigned, b) + 0x8000u;
    return (int)((ua >> 16) | (ub & 0xFFFF0000u));
}
#endif

// ---------------- fused prep: cast x -> bf16; transpose+cast both weights ----
static __device__ __forceinline__ void transpose_cast_tile(
    const float* __restrict__ W, short* __restrict__ Wt, int Kd, int N,
    int bx, int by)
{
    __shared__ float ts[32][33];
    const int c0 = bx * 32, r0 = by * 32;
    const int tx = threadIdx.x & 31, ty = threadIdx.x >> 5;   // ty 0..7
    #pragma unroll
    for (int e = 0; e < 4; ++e)
        ts[ty + e * 8][tx] = W[(size_t)(r0 + ty + e * 8) * N + c0 + tx];
    __syncthreads();
    #pragma unroll
    for (int e = 0; e < 4; ++e)
        Wt[(size_t)(c0 + ty + e * 8) * Kd + r0 + tx] = f2bf(ts[tx][ty + e * 8]);
}

__global__ __launch_bounds__(256) void prep_kernel(
    const float* __restrict__ x,      short* __restrict__ xb,    int nx,
    const float* __restrict__ W_qkv,  short* __restrict__ Wt1,
    const float* __restrict__ W_proj, short* __restrict__ Wt2,
    int C)
{
    const int nbx = nx / 1024;
    const int nb1 = (3 * C / 32) * (C / 32);
    int bid = blockIdx.x;
    if (bid < nbx) {
        int i = (bid * 256 + threadIdx.x) * 4;
        float4 v = *(const float4*)(x + i);
        short4v o = { f2bf(v.x), f2bf(v.y), f2bf(v.z), f2bf(v.w) };
        *(short4v*)(xb + i) = o;
        return;
    }
    bid -= nbx;
    if (bid < nb1) {
        const int nc = 3 * C / 32;
        transpose_cast_tile(W_qkv, Wt1, C, 3 * C, bid % nc, bid / nc);
        return;
    }
    bid -= nb1;
    {
        const int nc = C / 32;
        transpose_cast_tile(W_proj, Wt2, C, C, bid % nc, bid / nc);
    }
}

// ---------------- fused QKV GEMM + fragment-pack epilogue --------------------
// Round-11: GK 32 -> 64. K=1024 had 32 vmcnt(0)+barrier drains (the m97
// structure's known ~20% stall); GK=64 halves them and doubles compute per
// drain. Staging bytes identical; LDS As+Bs = 32KB fits the existing 34.8KB
// T-union; occupancy unchanged (grid-limited 3 blocks/CU).
// Bank-conflict trap at 128B row stride: fragment b128 reads would be 4-way.
// Fix per rule #21 (both-sides-or-neither, global_load_lds forbids padding):
// PRE-SWIZZLED GLOBAL SOURCE -- thread (sr,g) loads global k-granule
// g^(sr&7); LDS stays linear; reads XOR the same way:
// granule = (kk*4+quad) ^ (row&7). Enumerated spread = uniform 2-way (free).
// Epilogue (round 7/10 proven) unchanged: Q -> dense qb scaled; K/V staged in
// T (K token-major, V feat-major vec), fragment-packed kvp out.
// kvp[bh][ci][f][lane*8sh], f 0..3 = K(nb*2+half), f 4..7 = V(db).
#define GK 64

__global__ __launch_bounds__(256) void gemm_qkv_kernel(
    const short* __restrict__ A, const short* __restrict__ Bt,
    const float* __restrict__ bias,
    short* __restrict__ qb, short* __restrict__ kvp,
    int M, int N, int Kd, int C, int Ktok, float qscale)
{
    __shared__ __attribute__((aligned(16))) short smem[17408];  // 34.8KB union
    short* As = smem;            // [128*64], K-loop only
    short* Bs = smem + 8192;     // [128*64], K-loop only
    short* T  = smem;            // [128][136] epilogue staging (after barrier)

    const int tid  = threadIdx.x;
    const int lane = tid & 63, w = tid >> 6;
    const int col  = lane & 15, quad = lane >> 4;
    const int wm = (w & 1) * 64, wn = (w >> 1) * 64;

    // XCD-chunked swizzle (bijective: nwg % 8 == 0)
    const int nwg  = gridDim.x * gridDim.y;
    const int bid0 = blockIdx.y * gridDim.x + blockIdx.x;
    const int bid  = (bid0 & 7) * (nwg >> 3) + (bid0 >> 3);
    const int row0 = (bid / gridDim.x) * 128, col0 = (bid % gridDim.x) * 128;

    // staging: thread (sr = tid>>3, g = tid&7) loads global granule g^(sr&7)
    // of row sr -> LDS linear (tid*16B). 1 GLL16 = 32 rows.
    const int sr  = tid >> 3;
    const int sxg = ((tid & 7) ^ (sr & 7)) * 8;
    const short* gA = A  + (size_t)(row0 + sr) * Kd + sxg;
    const short* gB = Bt + (size_t)(col0 + sr) * Kd + sxg;
    short* lA = As + tid * 8;
    short* lB = Bs + tid * 8;
    const size_t skip32 = (size_t)32 * Kd;

    f32x4 acc[4][4] = {};
    for (int k0 = 0; k0 < Kd; k0 += GK) {
        __syncthreads();
        #pragma unroll
        for (int t = 0; t < 4; ++t) GLL16(gA + t * skip32, lA + t * 2048);
        #pragma unroll
        for (int t = 0; t < 4; ++t) GLL16(gB + t * skip32, lB + t * 2048);
        gA += GK; gB += GK;
        __syncthreads();

        #pragma unroll
        for (int kk = 0; kk < 2; ++kk) {
            short8 aF[4], bF[4];
            #pragma unroll
            for (int mt = 0; mt < 4; ++mt)
                aF[mt] = *(const short8*)&As[(wm + mt * 16 + col) * 64
                                             + (((kk * 4 + quad) ^ (col & 7)) * 8)];
            #pragma unroll
            for (int nt = 0; nt < 4; ++nt)
                bF[nt] = *(const short8*)&Bs[(wn + nt * 16 + col) * 64
                                             + (((kk * 4 + quad) ^ (col & 7)) * 8)];
            #pragma unroll
            for (int mt = 0; mt < 4; ++mt)
                #pragma unroll
                for (int nt = 0; nt < 4; ++nt)
                    acc[mt][nt] = __builtin_amdgcn_mfma_f32_16x16x32_bf16(aF[mt], bF[nt], acc[mt][nt], 0, 0, 0);
        }
    }

    if (col0 < C) {
        // ---- Q epilogue: scaled bf16 -> dense qb[M][C] ----
        #pragma unroll
        for (int mt = 0; mt < 4; ++mt)
            #pragma unroll
            for (int i = 0; i < 4; ++i) {
                const size_t r = row0 + wm + mt * 16 + quad * 4 + i;
                #pragma unroll
                for (int nt = 0; nt < 4; ++nt) {
                    const int c = col0 + wn + nt * 16 + col;
                    qb[r * C + c] = f2bf((acc[mt][nt][i] + bias[c]) * qscale);
                }
            }
        return;
    }

    // ---- K/V epilogue: stage tile in LDS, emit fragment-packed kvp ----
    const bool isK = col0 < 2 * C;
    __syncthreads();                         // all waves done with As/Bs
    #pragma unroll
    for (int mt = 0; mt < 4; ++mt) {
        const int rr0 = wm + mt * 16 + quad * 4;
        #pragma unroll
        for (int nt = 0; nt < 4; ++nt) {
            const int cr = wn + nt * 16 + col;           // feat_rel
            const float bb_ = bias[col0 + cr];
            if (isK) {                                   // token-major scalar
                #pragma unroll
                for (int i = 0; i < 4; ++i)
                    T[(rr0 + i) * 136 + cr] = f2bf(acc[mt][nt][i] + bb_);
            } else {                                     // feat-major VEC (8B)
                short4v pk = { f2bf(acc[mt][nt][0] + bb_),
                               f2bf(acc[mt][nt][1] + bb_),
                               f2bf(acc[mt][nt][2] + bb_),
                               f2bf(acc[mt][nt][3] + bb_) };
                *(short4v*)&T[cr * 136 + rr0] = pk;
            }
        }
    }
    __syncthreads();

    const int bb  = row0 / Ktok, k0t = row0 % Ktok;
    const int h0  = (col0 - (isK ? C : 2 * C)) >> 6;         // 2 heads/block
    #pragma unroll
    for (int j = 0; j < 8; ++j) {
        const int s     = tid + j * 256;                     // 0..2047
        const int lane2 = s & 63, f = (s >> 6) & 3, cil = (s >> 8) & 3, hl = s >> 10;
        const int col2  = lane2 & 15, quad2 = lane2 >> 4;
        short8 d;
        if (isK) {   // K frag f=nb*2+half: K[2*col2+nb][half*32+quad2*8 ..+8]
            const int nb = f >> 1, half = f & 1;
            d = *(const short8*)&T[(cil * 32 + 2 * col2 + nb) * 136
                                   + hl * 64 + half * 32 + quad2 * 8];
        } else {     // V frag f=db: V[quad2*8+j'][db*16+col2] via transposed T
            d = *(const short8*)&T[(hl * 64 + f * 16 + col2) * 136
                                   + cil * 32 + quad2 * 8];
        }
        const int bh = bb * 16 + h0 + hl;
        const int ci = (k0t >> 5) + cil;
        const int fr = isK ? f : 4 + f;
        *(short8*)(kvp + (((size_t)bh * 64 + ci) * 8 + fr) * 512 + lane2 * 8) = d;
    }
}

// ---------------- MFMA bf16 GEMM: C = A @ Bt^T + bias -----------------------
// Templated on tile (GM x GN); GK=64 with swizzled staging (see gemm_qkv).
// gemm3 at 128x64 -> 512 blocks = 2/CU; XCD-chunked swizzle (512%8==0).
template <typename OutT, int GM, int GN>
__global__ __launch_bounds__(256) void gemm_mfma_kernel(
    const short* __restrict__ A, const short* __restrict__ Bt,
    const float* __restrict__ bias, OutT* __restrict__ C,
    int M, int N, int Kd)
{
    constexpr int WM = GM / 2, WN = GN / 2;      // per-wave quadrant
    __shared__ __attribute__((aligned(16))) short As[GM * GK];
    __shared__ __attribute__((aligned(16))) short Bs[GN * GK];
    const int tid  = threadIdx.x;
    const int lane = tid & 63, w = tid >> 6;
    const int col  = lane & 15, quad = lane >> 4;
    const int wm = (w & 1) * WM, wn = (w >> 1) * WN;

    const int nwg  = gridDim.x * gridDim.y;
    const int bid0 = blockIdx.y * gridDim.x + blockIdx.x;
    const int bid  = (bid0 & 7) * (nwg >> 3) + (bid0 >> 3);
    const int row0 = (bid / gridDim.x) * GM, col0 = (bid % gridDim.x) * GN;

    const int sr  = tid >> 3;
    const int sxg = ((tid & 7) ^ (sr & 7)) * 8;
    const short* gA = A  + (size_t)(row0 + sr) * Kd + sxg;
    const short* gB = Bt + (size_t)(col0 + sr) * Kd + sxg;
    short* lA = As + tid * 8;
    short* lB = Bs + tid * 8;
    const size_t skip32 = (size_t)32 * Kd;

    f32x4 acc[WM / 16][WN / 16] = {};
    for (int k0 = 0; k0 < Kd; k0 += GK) {
        __syncthreads();
        #pragma unroll
        for (int t = 0; t < GM / 32; ++t) GLL16(gA + t * skip32, lA + t * 2048);
        #pragma unroll
        for (int t = 0; t < GN / 32; ++t) GLL16(gB + t * skip32, lB + t * 2048);
        gA += GK; gB += GK;
        __syncthreads();

        #pragma unroll
        for (int kk = 0; kk < 2; ++kk) {
            short8 aF[WM / 16], bF[WN / 16];
            #pragma unroll
            for (int mt = 0; mt < WM / 16; ++mt)
                aF[mt] = *(const short8*)&As[(wm + mt * 16 + col) * 64
                                             + (((kk * 4 + quad) ^ (col & 7)) * 8)];
            #pragma unroll
            for (int nt = 0; nt < WN / 16; ++nt)
                bF[nt] = *(const short8*)&Bs[(wn + nt * 16 + col) * 64
                                             + (((kk * 4 + quad) ^ (col & 7)) * 8)];
            #pragma unroll
            for (int mt = 0; mt < WM / 16; ++mt)
                #pragma unroll
                for (int nt = 0; nt < WN / 16; ++nt)
                    acc[mt][nt] = __builtin_amdgcn_mfma_f32_16x16x32_bf16(aF[mt], bF[nt], acc[mt][nt], 0, 0, 0);
        }
    }

    #pragma unroll
    for (int mt = 0; mt < WM / 16; ++mt)
        #pragma unroll
        for (int i = 0; i < 4; ++i) {
            const size_t r = row0 + wm + mt * 16 + quad * 4 + i;
            #pragma unroll
            for (int nt = 0; nt < WN / 16; ++nt) {
                const int c = col0 + wn + nt * 16 + col;
                store_out(&C[r * N + c], acc[mt][nt][i] + bias[c]);
            }
        }
}

// ---------------- MFMA flash attention — 32-q tiles, 4 waves/SIMD ------------
// ROUND-8 VERBATIM (best measured; VGPR 120, no demotion). Register-pipeline
// attempts (r6/r7/r9) all triggered scratch demotion or regressed; axis closed.
#define DH 64

__global__ __launch_bounds__(256, 4) void flash_mfma_kernel(
    const short* __restrict__ qb,     // bf16 [B*K][C] Q only (pre-scaled)
    const short* __restrict__ kvp,    // fragment-packed K/V
    short* __restrict__ y,            // bf16 [B,K,C]
    int K, int C)
{
    // Or region (2 x 32 x 68 f32 = 17408B) aliases the P region (5120 sh):
    // P is live only during the chunk loop, Or only after the __syncthreads().
    __shared__ __attribute__((aligned(16))) short smem[8704];

    const int tid  = threadIdx.x;
    const int lane = tid & 63, w = tid >> 6;
    const int col  = lane & 15, quad = lane >> 4;

    short* Pw = smem + w * 1280;           // 2 qg bufs x 640 sh, wave-private

    const int cmb = blockIdx.x & 31;       // b*16+h  (XCD-local: idx%8 tracks h)
    const int g   = blockIdx.x >> 5;       // pair index 0..31
    const int b   = cmb >> 4, h = cmb & 15;

    short8 bOnes;                          // L = P @ ones-column = rowsum
    #pragma unroll
    for (int j = 0; j < 8; ++j) bOnes[j] = (col == 0) ? (short)0x3F80 : (short)0;

    const short* qbase  = qb + (size_t)b * K * C + h * DH;
    const short* kvbase = kvp + (size_t)cmb * 64 * 4096 + lane * 8;

    struct Frag { short8 k[2][2]; short8 v[4]; };
    auto loadF = [&](Frag& f, int ci) {
        const short* p = kvbase + (size_t)ci * 4096;
        f.k[0][0] = *(const short8*)(p);
        f.k[0][1] = *(const short8*)(p + 512);
        f.k[1][0] = *(const short8*)(p + 1024);
        f.k[1][1] = *(const short8*)(p + 1536);
        f.v[0]    = *(const short8*)(p + 2048);
        f.v[1]    = *(const short8*)(p + 2560);
        f.v[2]    = *(const short8*)(p + 3072);
        f.v[3]    = *(const short8*)(p + 3584);
    };

    auto run = [&](int T) {
        const int t0 = T * 32;
        const int NC = T + 1;              // 32-key chunks in this tile

        short8 aQ[2][2];
        #pragma unroll
        for (int qg = 0; qg < 2; ++qg) {
            const short* qp = qbase + (size_t)(t0 + qg * 16 + col) * C;
            aQ[qg][0] = *(const short8*)(qp + quad * 8);
            aQ[qg][1] = *(const short8*)(qp + 32 + quad * 8);
        }
        f32x4 O[2][4] = {};
        f32x4 L4[2] = {};

        for (int ci = w; ci < NC; ci += 4) {
            Frag f;
            loadF(f, ci);
            const int kc = ci * 32;
            __builtin_amdgcn_s_setprio(1);
            #pragma unroll
            for (int qg = 0; qg < 2; ++qg) {
                const int qb2 = t0 + qg * 16;
                short* Ptq = Pw + qg * 640;            // private per (wave,qg)
                f32x4 S[2] = {};
                #pragma unroll
                for (int nb = 0; nb < 2; ++nb) {
                    S[nb] = __builtin_amdgcn_mfma_f32_16x16x32_bf16(aQ[qg][0], f.k[nb][0], S[nb], 0, 0, 0);
                    S[nb] = __builtin_amdgcn_mfma_f32_16x16x32_bf16(aQ[qg][1], f.k[nb][1], S[nb], 0, 0, 0);
                }
                if (kc + 31 <= qb2) {       // fully unmasked for this q-group
                    #pragma unroll
                    for (int i = 0; i < 4; ++i)
                        *(int*)&Ptq[(quad * 4 + i) * 40 + col * 2] =
                            pack2bf(EXP2(S[0][i]), EXP2(S[1][i]));
                } else {
                    const int kg = kc + col * 2;
                    #pragma unroll
                    for (int i = 0; i < 4; ++i) {
                        const int q = qb2 + quad * 4 + i;
                        float s0 = (kg + 0 <= q) ? S[0][i] : -INFINITY;
                        float s1 = (kg + 1 <= q) ? S[1][i] : -INFINITY;
                        *(int*)&Ptq[(quad * 4 + i) * 40 + col * 2] =
                            pack2bf(EXP2(s0), EXP2(s1));
                    }
                }
                // compiler inserts the minimal lgkmcnt for this buffer's RAW
                short8 aP = *(const short8*)&Ptq[col * 40 + quad * 8];
                #pragma unroll
                for (int db = 0; db < 4; ++db)
                    O[qg][db] = __builtin_amdgcn_mfma_f32_16x16x32_bf16(aP, f.v[db], O[qg][db], 0, 0, 0);
                L4[qg] = __builtin_amdgcn_mfma_f32_16x16x32_bf16(aP, bOnes, L4[qg], 0, 0, 0);
            }
            __builtin_amdgcn_s_setprio(0);
        }

        // ---- pairwise cross-wave reduction: w0->A, w1->B; w2+=A, w3+=B ----
        float* OrA = (float*)smem;               // 32 x 68 f32
        float* OrB = OrA + 32 * 68;
        __syncthreads();
        if (w < 2) {
            float* R = (w == 0) ? OrA : OrB;
            #pragma unroll
            for (int qg = 0; qg < 2; ++qg)
                #pragma unroll
                for (int i = 0; i < 4; ++i) {
                    const int row = qg * 16 + quad * 4 + i;
                    #pragma unroll
                    for (int db = 0; db < 4; ++db)
                        R[row * 68 + db * 16 + col] = O[qg][db][i];
                    if (col == 0) R[row * 68 + 64] = L4[qg][i];
                }
        }
        __syncthreads();
        if (w >= 2) {
            float* R = (w == 2) ? OrA : OrB;
            #pragma unroll
            for (int qg = 0; qg < 2; ++qg)
                #pragma unroll
                for (int i = 0; i < 4; ++i) {
                    const int row = qg * 16 + quad * 4 + i;
                    #pragma unroll
                    for (int db = 0; db < 4; ++db)
                        R[row * 68 + db * 16 + col] += O[qg][db][i];
                    if (col == 0) R[row * 68 + 64] += L4[qg][i];
                }
        }
        __syncthreads();

        // ---- combine A+B, normalize, store: wave w -> rows [w*8, w*8+8) ----
        #pragma unroll
        for (int rstep = 0; rstep < 2; ++rstep) {
            const int row = w * 8 + rstep * 4 + quad;
            f32x4 oa = *(const f32x4*)&OrA[row * 68 + col * 4];
            f32x4 ob = *(const f32x4*)&OrB[row * 68 + col * 4];
            const float inv = 1.f / (OrA[row * 68 + 64] + OrB[row * 68 + 64]);
            int2v o2 = { pack2bf((oa[0] + ob[0]) * inv, (oa[1] + ob[1]) * inv),
                         pack2bf((oa[2] + ob[2]) * inv, (oa[3] + ob[3]) * inv) };
            *(int2v*)(y + ((size_t)b * K + t0 + row) * C + h * DH + col * 4) = o2;
        }
        __syncthreads();   // protect Or/P alias before next tile restages
    };

    run(g);
    run(63 - g);
}

// ------------------------------- launch -------------------------------------
extern "C" void kernel_launch(void* const* d_in, const int* in_sizes, int n_in,
                              void* d_out, int out_size, void* d_ws, size_t ws_size,
                              hipStream_t stream)
{
    const float* x      = (const float*)d_in[0];
    const float* W_qkv  = (const float*)d_in[1];
    const float* b_qkv  = (const float*)d_in[2];
    const float* W_proj = (const float*)d_in[3];
    const float* b_proj = (const float*)d_in[4];

    const int B = 2, K = 2048, C = 1024, H = 16;
    const int M = B * K;   // 4096
    const float C2 = 0.18033688f;   // (1/sqrt(64)) * log2(e)

    char* ws = (char*)d_ws;
    short* xb    = (short*)ws;  ws += (size_t)M * C * 2;
    short* Wt1   = (short*)ws;  ws += (size_t)3 * C * C * 2;
    short* Wt2   = (short*)ws;  ws += (size_t)C * C * 2;
    short* qb    = (short*)ws;  ws += (size_t)M * C * 2;
    short* yb    = (short*)ws;  ws += (size_t)M * C * 2;
    short* kvp   = (short*)ws;  // 32 bh x 64 ci x 8 frag x 512 sh = 16.8 MB

    // prep (fused): cast x + transpose both weights
    const int nbx = (M * C) / 1024;
    const int nb1 = (3 * C / 32) * (C / 32);
    const int nb2 = (C / 32) * (C / 32);
    prep_kernel<<<nbx + nb1 + nb2, 256, 0, stream>>>(x, xb, M * C, W_qkv, Wt1, W_proj, Wt2, C);

    // 1) fused qkv GEMM: Q -> qb (pre-scaled), K/V -> kvp (fragment-packed)
    //    768 blocks = 3 blocks/CU; XCD-swizzled; GK=64
    dim3 g1((3 * C) / 128, M / 128);
    gemm_qkv_kernel<<<g1, 256, 0, stream>>>(xb, Wt1, b_qkv, qb, kvp, M, 3 * C, C, C, K, C2);

    // 2) flash attention -> yb (bf16); 1-D grid: idx = pair*32 + (b*16+h)
    //    32 pair-balanced 32-q tile-pairs x 32 bh = 1024 blocks (4/CU exact)
    flash_mfma_kernel<<<dim3(32 * 32), 256, 0, stream>>>(qb, kvp, yb, K, C);

    // 3) out = y @ W_proj + b_proj (fp32 out); 128x64 tile: 512 blocks = 2/CU
    dim3 g3(C / 64, M / 128);
    gemm_mfma_kernel<float, 128, 64><<<g3, 256, 0, stream>>>(yb, Wt2, b_proj, (float*)d_out, M, C, C);
}

// Round 12
// 175.120 us; speedup vs baseline: 1.0027x; 1.0027x over previous
//
#include <hip/hip_runtime.h>
#include <hip/hip_bf16.h>
#include <math.h>

typedef __attribute__((ext_vector_type(8))) short short8;
typedef __attribute__((ext_vector_type(4))) float f32x4;
typedef __attribute__((ext_vector_type(4))) short short4v;
typedef __attribute__((ext_vector_type(2))) int int2v;

static __device__ __forceinline__ short f2bf(float f) {
    __hip_bfloat16 h = __float2bfloat16(f);
    return *reinterpret_cast<short*>(&h);
}
static __device__ __forceinline__ void store_out(float* p, float v) { *p = v; }
static __device__ __forceinline__ void store_out(short* p, float v) { *p = f2bf(v); }

#define GLL16(g, l) __builtin_amdgcn_global_load_lds( \
    (const __attribute__((address_space(1))) void*)(g), \
    (__attribute__((address_space(3))) void*)(l), 16, 0, 0)

#if __has_builtin(__builtin_amdgcn_exp2f)
#define EXP2(x) __builtin_amdgcn_exp2f(x)
#else
#define EXP2(x) exp2f(x)
#endif

// pack two f32 -> packed bf16 pair (low = a, high = b)
#if __has_builtin(__builtin_amdgcn_cvt_pk_bf16_f32)
typedef __attribute__((ext_vector_type(2))) __bf16 bf16x2;
static __device__ __forceinline__ int pack2bf(float a, float b) {
    bf16x2 r = __builtin_amdgcn_cvt_pk_bf16_f32(a, b);
    return __builtin_bit_cast(int, r);
}
#else
static __device__ __forceinline__ int pack2bf(float a, float b) {
    unsigned ua = __builtin_bit_cast(unsigned, a) + 0x8000u;
    unsigned ub = __builtin_bit_cast(unsigned, b) + 0x8000u;
    return (int)((ua >> 16) | (ub & 0xFFFF0000u));
}
#endif

// ---------------- fused prep: cast x -> bf16; transpose+cast both weights ----
static __device__ __forceinline__ void transpose_cast_tile(
    const float* __restrict__ W, short* __restrict__ Wt, int Kd, int N,
    int bx, int by)
{
    __shared__ float ts[32][33];
    const int c0 = bx * 32, r0 = by * 32;
    const int tx = threadIdx.x & 31, ty = threadIdx.x >> 5;   // ty 0..7
    #pragma unroll
    for (int e = 0; e < 4; ++e)
        ts[ty + e * 8][tx] = W[(size_t)(r0 + ty + e * 8) * N + c0 + tx];
    __syncthreads();
    #pragma unroll
    for (int e = 0; e < 4; ++e)
        Wt[(size_t)(c0 + ty + e * 8) * Kd + r0 + tx] = f2bf(ts[tx][ty + e * 8]);
}

__global__ __launch_bounds__(256) void prep_kernel(
    const float* __restrict__ x,      short* __restrict__ xb,    int nx,
    const float* __restrict__ W_qkv,  short* __restrict__ Wt1,
    const float* __restrict__ W_proj, short* __restrict__ Wt2,
    int C)
{
    const int nbx = nx / 1024;
    const int nb1 = (3 * C / 32) * (C / 32);
    int bid = blockIdx.x;
    if (bid < nbx) {
        int i = (bid * 256 + threadIdx.x) * 4;
        float4 v = *(const float4*)(x + i);
        short4v o = { f2bf(v.x), f2bf(v.y), f2bf(v.z), f2bf(v.w) };
        *(short4v*)(xb + i) = o;
        return;
    }
    bid -= nbx;
    if (bid < nb1) {
        const int nc = 3 * C / 32;
        transpose_cast_tile(W_qkv, Wt1, C, 3 * C, bid % nc, bid / nc);
        return;
    }
    bid -= nb1;
    {
        const int nc = C / 32;
        transpose_cast_tile(W_proj, Wt2, C, C, bid % nc, bid / nc);
    }
}

// ---------------- fused QKV GEMM + fragment-pack epilogue --------------------
// Round-12: round-10 structure (GK=32, proven 171.6us total) + the granule-XOR
// conflict fix that r11 PROVED works (3.24M -> 98K) but bundled with a harmful
// GK=64. r11 decomposition: conflicts were the MAIN-LOOP fragment reads
// (slot = 16*(row&1)+4*quad -> 8 lanes/slot = 8-way, ~2.9x per m136); the
// GK=64 regression came from destroyed L2 streaming (FETCH 2x) + occupancy.
// Fix at GK=32 (rule #21, both-sides-or-neither):
//   source: thread (sr,g) loads global granule g^((sr>>1)&3); LDS linear.
//   read:   offset (quad ^ ((col>>1)&3))*8   [lane-constant, 0 extra VALU]
// -> 2 lanes/slot with different (row>>1) = uniform 2-way = free.
// Per-GLL16 transaction set identical to r10 (permutation within each row's
// 64B) -> FETCH/occupancy unchanged. Results bitwise identical.
// Epilogue (round 7/10 proven) unchanged. kvp[bh][ci][f][lane*8sh],
// f 0..3 = K(nb*2+half), f 4..7 = V(db).
#define GK 32

__global__ __launch_bounds__(256) void gemm_qkv_kernel(
    const short* __restrict__ A, const short* __restrict__ Bt,
    const float* __restrict__ bias,
    short* __restrict__ qb, short* __restrict__ kvp,
    int M, int N, int Kd, int C, int Ktok, float qscale)
{
    __shared__ __attribute__((aligned(16))) short smem[17408];  // 34.8KB union
    short* As = smem;            // [128*32], K-loop only
    short* Bs = smem + 4096;     // [128*32], K-loop only
    short* T  = smem;            // [128][136] epilogue staging (after barrier)

    const int tid  = threadIdx.x;
    const int lane = tid & 63, w = tid >> 6;
    const int col  = lane & 15, quad = lane >> 4;
    const int wm = (w & 1) * 64, wn = (w >> 1) * 64;

    // XCD-chunked swizzle (bijective: nwg % 8 == 0)
    const int nwg  = gridDim.x * gridDim.y;
    const int bid0 = blockIdx.y * gridDim.x + blockIdx.x;
    const int bid  = (bid0 & 7) * (nwg >> 3) + (bid0 >> 3);
    const int row0 = (bid / gridDim.x) * 128, col0 = (bid % gridDim.x) * 128;

    // staging: thread (sr=tid>>2, g=tid&3) loads global granule g^((sr>>1)&3)
    // of row sr; LDS linear (tid*16B). Same 16-rows-x-64B set per GLL16 as r10.
    const int sr  = tid >> 2;
    const int sxg = ((tid & 3) ^ ((sr >> 1) & 3)) * 8;
    const short* gA = A  + (size_t)(row0 + sr) * Kd + sxg;
    const short* gB = Bt + (size_t)(col0 + sr) * Kd + sxg;
    short* lA = As + tid * 8;
    short* lB = Bs + tid * 8;
    const size_t skip = (size_t)64 * Kd;

    const int xr8 = (quad ^ ((col >> 1) & 3)) * 8;   // swizzled read offset

    f32x4 acc[4][4] = {};
    for (int k0 = 0; k0 < Kd; k0 += GK) {
        __syncthreads();
        GLL16(gA,        lA);
        GLL16(gA + skip, lA + 64 * GK);
        GLL16(gB,        lB);
        GLL16(gB + skip, lB + 64 * GK);
        gA += GK; gB += GK;
        __syncthreads();

        short8 aF[4], bF[4];
        #pragma unroll
        for (int mt = 0; mt < 4; ++mt)
            aF[mt] = *(const short8*)&As[(wm + mt * 16 + col) * GK + xr8];
        #pragma unroll
        for (int nt = 0; nt < 4; ++nt)
            bF[nt] = *(const short8*)&Bs[(wn + nt * 16 + col) * GK + xr8];
        #pragma unroll
        for (int mt = 0; mt < 4; ++mt)
            #pragma unroll
            for (int nt = 0; nt < 4; ++nt)
                acc[mt][nt] = __builtin_amdgcn_mfma_f32_16x16x32_bf16(aF[mt], bF[nt], acc[mt][nt], 0, 0, 0);
    }

    if (col0 < C) {
        // ---- Q epilogue: scaled bf16 -> dense qb[M][C] ----
        #pragma unroll
        for (int mt = 0; mt < 4; ++mt)
            #pragma unroll
            for (int i = 0; i < 4; ++i) {
                const size_t r = row0 + wm + mt * 16 + quad * 4 + i;
                #pragma unroll
                for (int nt = 0; nt < 4; ++nt) {
                    const int c = col0 + wn + nt * 16 + col;
                    qb[r * C + c] = f2bf((acc[mt][nt][i] + bias[c]) * qscale);
                }
            }
        return;
    }

    // ---- K/V epilogue: stage tile in LDS, emit fragment-packed kvp ----
    const bool isK = col0 < 2 * C;
    __syncthreads();                         // all waves done with As/Bs
    #pragma unroll
    for (int mt = 0; mt < 4; ++mt) {
        const int rr0 = wm + mt * 16 + quad * 4;
        #pragma unroll
        for (int nt = 0; nt < 4; ++nt) {
            const int cr = wn + nt * 16 + col;           // feat_rel
            const float bb_ = bias[col0 + cr];
            if (isK) {                                   // token-major scalar
                #pragma unroll
                for (int i = 0; i < 4; ++i)
                    T[(rr0 + i) * 136 + cr] = f2bf(acc[mt][nt][i] + bb_);
            } else {                                     // feat-major VEC (8B)
                short4v pk = { f2bf(acc[mt][nt][0] + bb_),
                               f2bf(acc[mt][nt][1] + bb_),
                               f2bf(acc[mt][nt][2] + bb_),
                               f2bf(acc[mt][nt][3] + bb_) };
                *(short4v*)&T[cr * 136 + rr0] = pk;
            }
        }
    }
    __syncthreads();

    const int bb  = row0 / Ktok, k0t = row0 % Ktok;
    const int h0  = (col0 - (isK ? C : 2 * C)) >> 6;         // 2 heads/block
    #pragma unroll
    for (int j = 0; j < 8; ++j) {
        const int s     = tid + j * 256;                     // 0..2047
        const int lane2 = s & 63, f = (s >> 6) & 3, cil = (s >> 8) & 3, hl = s >> 10;
        const int col2  = lane2 & 15, quad2 = lane2 >> 4;
        short8 d;
        if (isK) {   // K frag f=nb*2+half: K[2*col2+nb][half*32+quad2*8 ..+8]
            const int nb = f >> 1, half = f & 1;
            d = *(const short8*)&T[(cil * 32 + 2 * col2 + nb) * 136
                                   + hl * 64 + half * 32 + quad2 * 8];
        } else {     // V frag f=db: V[quad2*8+j'][db*16+col2] via transposed T
            d = *(const short8*)&T[(hl * 64 + f * 16 + col2) * 136
                                   + cil * 32 + quad2 * 8];
        }
        const int bh = bb * 16 + h0 + hl;
        const int ci = (k0t >> 5) + cil;
        const int fr = isK ? f : 4 + f;
        *(short8*)(kvp + (((size_t)bh * 64 + ci) * 8 + fr) * 512 + lane2 * 8) = d;
    }
}

// ---------------- MFMA bf16 GEMM: C = A @ Bt^T + bias -----------------------
// Round-10 structure (GK=32) + granule-XOR swizzle (see gemm_qkv).
// gemm3 at 128x64 -> 512 blocks = 2/CU; XCD-chunked swizzle (512%8==0).
template <typename OutT, int GM, int GN>
__global__ __launch_bounds__(256) void gemm_mfma_kernel(
    const short* __restrict__ A, const short* __restrict__ Bt,
    const float* __restrict__ bias, OutT* __restrict__ C,
    int M, int N, int Kd)
{
    constexpr int WM = GM / 2, WN = GN / 2;      // per-wave quadrant
    __shared__ __attribute__((aligned(16))) short As[GM * GK];
    __shared__ __attribute__((aligned(16))) short Bs[GN * GK];
    const int tid  = threadIdx.x;
    const int lane = tid & 63, w = tid >> 6;
    const int col  = lane & 15, quad = lane >> 4;
    const int wm = (w & 1) * WM, wn = (w >> 1) * WN;

    const int nwg  = gridDim.x * gridDim.y;
    const int bid0 = blockIdx.y * gridDim.x + blockIdx.x;
    const int bid  = (bid0 & 7) * (nwg >> 3) + (bid0 >> 3);
    const int row0 = (bid / gridDim.x) * GM, col0 = (bid % gridDim.x) * GN;

    const int sr  = tid >> 2;
    const int sxg = ((tid & 3) ^ ((sr >> 1) & 3)) * 8;
    const short* gA = A  + (size_t)(row0 + sr) * Kd + sxg;
    const short* gB = Bt + (size_t)(col0 + sr) * Kd + sxg;
    short* lA = As + tid * 8;
    short* lB = Bs + tid * 8;
    const size_t skip = (size_t)64 * Kd;

    const int xr8 = (quad ^ ((col >> 1) & 3)) * 8;   // swizzled read offset

    f32x4 acc[WM / 16][WN / 16] = {};
    for (int k0 = 0; k0 < Kd; k0 += GK) {
        __syncthreads();
        #pragma unroll
        for (int t = 0; t < GM / 64; ++t) GLL16(gA + t * skip, lA + t * 64 * GK);
        #pragma unroll
        for (int t = 0; t < GN / 64; ++t) GLL16(gB + t * skip, lB + t * 64 * GK);
        gA += GK; gB += GK;
        __syncthreads();

        short8 aF[WM / 16], bF[WN / 16];
        #pragma unroll
        for (int mt = 0; mt < WM / 16; ++mt)
            aF[mt] = *(const short8*)&As[(wm + mt * 16 + col) * GK + xr8];
        #pragma unroll
        for (int nt = 0; nt < WN / 16; ++nt)
            bF[nt] = *(const short8*)&Bs[(wn + nt * 16 + col) * GK + xr8];
        #pragma unroll
        for (int mt = 0; mt < WM / 16; ++mt)
            #pragma unroll
            for (int nt = 0; nt < WN / 16; ++nt)
                acc[mt][nt] = __builtin_amdgcn_mfma_f32_16x16x32_bf16(aF[mt], bF[nt], acc[mt][nt], 0, 0, 0);
    }

    #pragma unroll
    for (int mt = 0; mt < WM / 16; ++mt)
        #pragma unroll
        for (int i = 0; i < 4; ++i) {
            const size_t r = row0 + wm + mt * 16 + quad * 4 + i;
            #pragma unroll
            for (int nt = 0; nt < WN / 16; ++nt) {
                const int c = col0 + wn + nt * 16 + col;
                store_out(&C[r * N + c], acc[mt][nt][i] + bias[c]);
            }
        }
}

// ---------------- MFMA flash attention — 32-q tiles, 4 waves/SIMD ------------
// ROUND-8 VERBATIM (best measured; VGPR 120, no demotion). Register-pipeline
// attempts (r6/r7/r9) all triggered scratch demotion or regressed; axis closed.
#define DH 64

__global__ __launch_bounds__(256, 4) void flash_mfma_kernel(
    const short* __restrict__ qb,     // bf16 [B*K][C] Q only (pre-scaled)
    const short* __restrict__ kvp,    // fragment-packed K/V
    short* __restrict__ y,            // bf16 [B,K,C]
    int K, int C)
{
    // Or region (2 x 32 x 68 f32 = 17408B) aliases the P region (5120 sh):
    // P is live only during the chunk loop, Or only after the __syncthreads().
    __shared__ __attribute__((aligned(16))) short smem[8704];

    const int tid  = threadIdx.x;
    const int lane = tid & 63, w = tid >> 6;
    const int col  = lane & 15, quad = lane >> 4;

    short* Pw = smem + w * 1280;           // 2 qg bufs x 640 sh, wave-private

    const int cmb = blockIdx.x & 31;       // b*16+h  (XCD-local: idx%8 tracks h)
    const int g   = blockIdx.x >> 5;       // pair index 0..31
    const int b   = cmb >> 4, h = cmb & 15;

    short8 bOnes;                          // L = P @ ones-column = rowsum
    #pragma unroll
    for (int j = 0; j < 8; ++j) bOnes[j] = (col == 0) ? (short)0x3F80 : (short)0;

    const short* qbase  = qb + (size_t)b * K * C + h * DH;
    const short* kvbase = kvp + (size_t)cmb * 64 * 4096 + lane * 8;

    struct Frag { short8 k[2][2]; short8 v[4]; };
    auto loadF = [&](Frag& f, int ci) {
        const short* p = kvbase + (size_t)ci * 4096;
        f.k[0][0] = *(const short8*)(p);
        f.k[0][1] = *(const short8*)(p + 512);
        f.k[1][0] = *(const short8*)(p + 1024);
        f.k[1][1] = *(const short8*)(p + 1536);
        f.v[0]    = *(const short8*)(p + 2048);
        f.v[1]    = *(const short8*)(p + 2560);
        f.v[2]    = *(const short8*)(p + 3072);
        f.v[3]    = *(const short8*)(p + 3584);
    };

    auto run = [&](int T) {
        const int t0 = T * 32;
        const int NC = T + 1;              // 32-key chunks in this tile

        short8 aQ[2][2];
        #pragma unroll
        for (int qg = 0; qg < 2; ++qg) {
            const short* qp = qbase + (size_t)(t0 + qg * 16 + col) * C;
            aQ[qg][0] = *(const short8*)(qp + quad * 8);
            aQ[qg][1] = *(const short8*)(qp + 32 + quad * 8);
        }
        f32x4 O[2][4] = {};
        f32x4 L4[2] = {};

        for (int ci = w; ci < NC; ci += 4) {
            Frag f;
            loadF(f, ci);
            const int kc = ci * 32;
            __builtin_amdgcn_s_setprio(1);
            #pragma unroll
            for (int qg = 0; qg < 2; ++qg) {
                const int qb2 = t0 + qg * 16;
                short* Ptq = Pw + qg * 640;            // private per (wave,qg)
                f32x4 S[2] = {};
                #pragma unroll
                for (int nb = 0; nb < 2; ++nb) {
                    S[nb] = __builtin_amdgcn_mfma_f32_16x16x32_bf16(aQ[qg][0], f.k[nb][0], S[nb], 0, 0, 0);
                    S[nb] = __builtin_amdgcn_mfma_f32_16x16x32_bf16(aQ[qg][1], f.k[nb][1], S[nb], 0, 0, 0);
                }
                if (kc + 31 <= qb2) {       // fully unmasked for this q-group
                    #pragma unroll
                    for (int i = 0; i < 4; ++i)
                        *(int*)&Ptq[(quad * 4 + i) * 40 + col * 2] =
                            pack2bf(EXP2(S[0][i]), EXP2(S[1][i]));
                } else {
                    const int kg = kc + col * 2;
                    #pragma unroll
                    for (int i = 0; i < 4; ++i) {
                        const int q = qb2 + quad * 4 + i;
                        float s0 = (kg + 0 <= q) ? S[0][i] : -INFINITY;
                        float s1 = (kg + 1 <= q) ? S[1][i] : -INFINITY;
                        *(int*)&Ptq[(quad * 4 + i) * 40 + col * 2] =
                            pack2bf(EXP2(s0), EXP2(s1));
                    }
                }
                // compiler inserts the minimal lgkmcnt for this buffer's RAW
                short8 aP = *(const short8*)&Ptq[col * 40 + quad * 8];
                #pragma unroll
                for (int db = 0; db < 4; ++db)
                    O[qg][db] = __builtin_amdgcn_mfma_f32_16x16x32_bf16(aP, f.v[db], O[qg][db], 0, 0, 0);
                L4[qg] = __builtin_amdgcn_mfma_f32_16x16x32_bf16(aP, bOnes, L4[qg], 0, 0, 0);
            }
            __builtin_amdgcn_s_setprio(0);
        }

        // ---- pairwise cross-wave reduction: w0->A, w1->B; w2+=A, w3+=B ----
        float* OrA = (float*)smem;               // 32 x 68 f32
        float* OrB = OrA + 32 * 68;
        __syncthreads();
        if (w < 2) {
            float* R = (w == 0) ? OrA : OrB;
            #pragma unroll
            for (int qg = 0; qg < 2; ++qg)
                #pragma unroll
                for (int i = 0; i < 4; ++i) {
                    const int row = qg * 16 + quad * 4 + i;
                    #pragma unroll
                    for (int db = 0; db < 4; ++db)
                        R[row * 68 + db * 16 + col] = O[qg][db][i];
                    if (col == 0) R[row * 68 + 64] = L4[qg][i];
                }
        }
        __syncthreads();
        if (w >= 2) {
            float* R = (w == 2) ? OrA : OrB;
            #pragma unroll
            for (int qg = 0; qg < 2; ++qg)
                #pragma unroll
                for (int i = 0; i < 4; ++i) {
                    const int row = qg * 16 + quad * 4 + i;
                    #pragma unroll
                    for (int db = 0; db < 4; ++db)
                        R[row * 68 + db * 16 + col] += O[qg][db][i];
                    if (col == 0) R[row * 68 + 64] += L4[qg][i];
                }
        }
        __syncthreads();

        // ---- combine A+B, normalize, store: wave w -> rows [w*8, w*8+8) ----
        #pragma unroll
        for (int rstep = 0; rstep < 2; ++rstep) {
            const int row = w * 8 + rstep * 4 + quad;
            f32x4 oa = *(const f32x4*)&OrA[row * 68 + col * 4];
            f32x4 ob = *(const f32x4*)&OrB[row * 68 + col * 4];
            const float inv = 1.f / (OrA[row * 68 + 64] + OrB[row * 68 + 64]);
            int2v o2 = { pack2bf((oa[0] + ob[0]) * inv, (oa[1] + ob[1]) * inv),
                         pack2bf((oa[2] + ob[2]) * inv, (oa[3] + ob[3]) * inv) };
            *(int2v*)(y + ((size_t)b * K + t0 + row) * C + h * DH + col * 4) = o2;
        }
        __syncthreads();   // protect Or/P alias before next tile restages
    };

    run(g);
    run(63 - g);
}

// ------------------------------- launch -------------------------------------
extern "C" void kernel_launch(void* const* d_in, const int* in_sizes, int n_in,
                              void* d_out, int out_size, void* d_ws, size_t ws_size,
                              hipStream_t stream)
{
    const float* x      = (const float*)d_in[0];
    const float* W_qkv  = (const float*)d_in[1];
    const float* b_qkv  = (const float*)d_in[2];
    const float* W_proj = (const float*)d_in[3];
    const float* b_proj = (const float*)d_in[4];

    const int B = 2, K = 2048, C = 1024, H = 16;
    const int M = B * K;   // 4096
    const float C2 = 0.18033688f;   // (1/sqrt(64)) * log2(e)

    char* ws = (char*)d_ws;
    short* xb    = (short*)ws;  ws += (size_t)M * C * 2;
    short* Wt1   = (short*)ws;  ws += (size_t)3 * C * C * 2;
    short* Wt2   = (short*)ws;  ws += (size_t)C * C * 2;
    short* qb    = (short*)ws;  ws += (size_t)M * C * 2;
    short* yb    = (short*)ws;  ws += (size_t)M * C * 2;
    short* kvp   = (short*)ws;  // 32 bh x 64 ci x 8 frag x 512 sh = 16.8 MB

    // prep (fused): cast x + transpose both weights
    const int nbx = (M * C) / 1024;
    const int nb1 = (3 * C / 32) * (C / 32);
    const int nb2 = (C / 32) * (C / 32);
    prep_kernel<<<nbx + nb1 + nb2, 256, 0, stream>>>(x, xb, M * C, W_qkv, Wt1, W_proj, Wt2, C);

    // 1) fused qkv GEMM: Q -> qb (pre-scaled), K/V -> kvp (fragment-packed)
    //    768 blocks = 3 blocks/CU; XCD-swizzled; GK=32 + granule-XOR swizzle
    dim3 g1((3 * C) / 128, M / 128);
    gemm_qkv_kernel<<<g1, 256, 0, stream>>>(xb, Wt1, b_qkv, qb, kvp, M, 3 * C, C, C, K, C2);

    // 2) flash attention -> yb (bf16); 1-D grid: idx = pair*32 + (b*16+h)
    //    32 pair-balanced 32-q tile-pairs x 32 bh = 1024 blocks (4/CU exact)
    flash_mfma_kernel<<<dim3(32 * 32), 256, 0, stream>>>(qb, kvp, yb, K, C);

    // 3) out = y @ W_proj + b_proj (fp32 out); 128x64 tile: 512 blocks = 2/CU
    dim3 g3(C / 64, M / 128);
    gemm_mfma_kernel<float, 128, 64><<<g3, 256, 0, stream>>>(yb, Wt2, b_proj, (float*)d_out, M, C, C);
}

// Round 13
// 170.708 us; speedup vs baseline: 1.0286x; 1.0258x over previous
//
#include <hip/hip_runtime.h>
#include <hip/hip_bf16.h>
#include <math.h>

typedef __attribute__((ext_vector_type(8))) short short8;
typedef __attribute__((ext_vector_type(4))) float f32x4;
typedef __attribute__((ext_vector_type(4))) short short4v;
typedef __attribute__((ext_vector_type(2))) int int2v;

static __device__ __forceinline__ short f2bf(float f) {
    __hip_bfloat16 h = __float2bfloat16(f);
    return *reinterpret_cast<short*>(&h);
}
static __device__ __forceinline__ void store_out(float* p, float v) { *p = v; }
static __device__ __forceinline__ void store_out(short* p, float v) { *p = f2bf(v); }

#define GLL16(g, l) __builtin_amdgcn_global_load_lds( \
    (const __attribute__((address_space(1))) void*)(g), \
    (__attribute__((address_space(3))) void*)(l), 16, 0, 0)

#if __has_builtin(__builtin_amdgcn_exp2f)
#define EXP2(x) __builtin_amdgcn_exp2f(x)
#else
#define EXP2(x) exp2f(x)
#endif

// pack two f32 -> packed bf16 pair (low = a, high = b)
#if __has_builtin(__builtin_amdgcn_cvt_pk_bf16_f32)
typedef __attribute__((ext_vector_type(2))) __bf16 bf16x2;
static __device__ __forceinline__ int pack2bf(float a, float b) {
    bf16x2 r = __builtin_amdgcn_cvt_pk_bf16_f32(a, b);
    return __builtin_bit_cast(int, r);
}
#else
static __device__ __forceinline__ int pack2bf(float a, float b) {
    unsigned ua = __builtin_bit_cast(unsigned, a) + 0x8000u;
    unsigned ub = __builtin_bit_cast(unsigned, b) + 0x8000u;
    return (int)((ua >> 16) | (ub & 0xFFFF0000u));
}
#endif

// ---------------- fused prep: cast x -> bf16; transpose+cast both weights ----
static __device__ __forceinline__ void transpose_cast_tile(
    const float* __restrict__ W, short* __restrict__ Wt, int Kd, int N,
    int bx, int by)
{
    __shared__ float ts[32][33];
    const int c0 = bx * 32, r0 = by * 32;
    const int tx = threadIdx.x & 31, ty = threadIdx.x >> 5;   // ty 0..7
    #pragma unroll
    for (int e = 0; e < 4; ++e)
        ts[ty + e * 8][tx] = W[(size_t)(r0 + ty + e * 8) * N + c0 + tx];
    __syncthreads();
    #pragma unroll
    for (int e = 0; e < 4; ++e)
        Wt[(size_t)(c0 + ty + e * 8) * Kd + r0 + tx] = f2bf(ts[tx][ty + e * 8]);
}

__global__ __launch_bounds__(256) void prep_kernel(
    const float* __restrict__ x,      short* __restrict__ xb,    int nx,
    const float* __restrict__ W_qkv,  short* __restrict__ Wt1,
    const float* __restrict__ W_proj, short* __restrict__ Wt2,
    int C)
{
    const int nbx = nx / 1024;
    const int nb1 = (3 * C / 32) * (C / 32);
    int bid = blockIdx.x;
    if (bid < nbx) {
        int i = (bid * 256 + threadIdx.x) * 4;
        float4 v = *(const float4*)(x + i);
        short4v o = { f2bf(v.x), f2bf(v.y), f2bf(v.z), f2bf(v.w) };
        *(short4v*)(xb + i) = o;
        return;
    }
    bid -= nbx;
    if (bid < nb1) {
        const int nc = 3 * C / 32;
        transpose_cast_tile(W_qkv, Wt1, C, 3 * C, bid % nc, bid / nc);
        return;
    }
    bid -= nb1;
    {
        const int nc = C / 32;
        transpose_cast_tile(W_proj, Wt2, C, C, bid % nc, bid / nc);
    }
}

// ---------------- fused QKV GEMM + fragment-pack epilogue --------------------
// ROUND-12 VERBATIM (kernel-level proven: bank conflicts 3.24M -> 98K,
// dur 43.8 -> 41.6us, FETCH/occupancy unchanged). GK=32 + granule-XOR swizzle:
//   source: thread (sr,g) loads global granule g^((sr>>1)&3); LDS linear.
//   read:   offset (quad ^ ((col>>1)&3))*8   [lane-constant, 0 extra VALU]
// XCD-chunked blockIdx swizzle (768%8==0 bijective) for A-panel L2 reuse.
// Epilogue: Q -> dense qb scaled; K/V staged in T (K token-major, V feat-major
// vec), fragment-packed kvp out. kvp[bh][ci][f][lane*8sh], f 0..3 =
// K(nb*2+half), f 4..7 = V(db).
#define GK 32

__global__ __launch_bounds__(256) void gemm_qkv_kernel(
    const short* __restrict__ A, const short* __restrict__ Bt,
    const float* __restrict__ bias,
    short* __restrict__ qb, short* __restrict__ kvp,
    int M, int N, int Kd, int C, int Ktok, float qscale)
{
    __shared__ __attribute__((aligned(16))) short smem[17408];  // 34.8KB union
    short* As = smem;            // [128*32], K-loop only
    short* Bs = smem + 4096;     // [128*32], K-loop only
    short* T  = smem;            // [128][136] epilogue staging (after barrier)

    const int tid  = threadIdx.x;
    const int lane = tid & 63, w = tid >> 6;
    const int col  = lane & 15, quad = lane >> 4;
    const int wm = (w & 1) * 64, wn = (w >> 1) * 64;

    // XCD-chunked swizzle (bijective: nwg % 8 == 0)
    const int nwg  = gridDim.x * gridDim.y;
    const int bid0 = blockIdx.y * gridDim.x + blockIdx.x;
    const int bid  = (bid0 & 7) * (nwg >> 3) + (bid0 >> 3);
    const int row0 = (bid / gridDim.x) * 128, col0 = (bid % gridDim.x) * 128;

    const int sr  = tid >> 2;
    const int sxg = ((tid & 3) ^ ((sr >> 1) & 3)) * 8;
    const short* gA = A  + (size_t)(row0 + sr) * Kd + sxg;
    const short* gB = Bt + (size_t)(col0 + sr) * Kd + sxg;
    short* lA = As + tid * 8;
    short* lB = Bs + tid * 8;
    const size_t skip = (size_t)64 * Kd;

    const int xr8 = (quad ^ ((col >> 1) & 3)) * 8;   // swizzled read offset

    f32x4 acc[4][4] = {};
    for (int k0 = 0; k0 < Kd; k0 += GK) {
        __syncthreads();
        GLL16(gA,        lA);
        GLL16(gA + skip, lA + 64 * GK);
        GLL16(gB,        lB);
        GLL16(gB + skip, lB + 64 * GK);
        gA += GK; gB += GK;
        __syncthreads();

        short8 aF[4], bF[4];
        #pragma unroll
        for (int mt = 0; mt < 4; ++mt)
            aF[mt] = *(const short8*)&As[(wm + mt * 16 + col) * GK + xr8];
        #pragma unroll
        for (int nt = 0; nt < 4; ++nt)
            bF[nt] = *(const short8*)&Bs[(wn + nt * 16 + col) * GK + xr8];
        #pragma unroll
        for (int mt = 0; mt < 4; ++mt)
            #pragma unroll
            for (int nt = 0; nt < 4; ++nt)
                acc[mt][nt] = __builtin_amdgcn_mfma_f32_16x16x32_bf16(aF[mt], bF[nt], acc[mt][nt], 0, 0, 0);
    }

    if (col0 < C) {
        // ---- Q epilogue: scaled bf16 -> dense qb[M][C] ----
        #pragma unroll
        for (int mt = 0; mt < 4; ++mt)
            #pragma unroll
            for (int i = 0; i < 4; ++i) {
                const size_t r = row0 + wm + mt * 16 + quad * 4 + i;
                #pragma unroll
                for (int nt = 0; nt < 4; ++nt) {
                    const int c = col0 + wn + nt * 16 + col;
                    qb[r * C + c] = f2bf((acc[mt][nt][i] + bias[c]) * qscale);
                }
            }
        return;
    }

    // ---- K/V epilogue: stage tile in LDS, emit fragment-packed kvp ----
    const bool isK = col0 < 2 * C;
    __syncthreads();                         // all waves done with As/Bs
    #pragma unroll
    for (int mt = 0; mt < 4; ++mt) {
        const int rr0 = wm + mt * 16 + quad * 4;
        #pragma unroll
        for (int nt = 0; nt < 4; ++nt) {
            const int cr = wn + nt * 16 + col;           // feat_rel
            const float bb_ = bias[col0 + cr];
            if (isK) {                                   // token-major scalar
                #pragma unroll
                for (int i = 0; i < 4; ++i)
                    T[(rr0 + i) * 136 + cr] = f2bf(acc[mt][nt][i] + bb_);
            } else {                                     // feat-major VEC (8B)
                short4v pk = { f2bf(acc[mt][nt][0] + bb_),
                               f2bf(acc[mt][nt][1] + bb_),
                               f2bf(acc[mt][nt][2] + bb_),
                               f2bf(acc[mt][nt][3] + bb_) };
                *(short4v*)&T[cr * 136 + rr0] = pk;
            }
        }
    }
    __syncthreads();

    const int bb  = row0 / Ktok, k0t = row0 % Ktok;
    const int h0  = (col0 - (isK ? C : 2 * C)) >> 6;         // 2 heads/block
    #pragma unroll
    for (int j = 0; j < 8; ++j) {
        const int s     = tid + j * 256;                     // 0..2047
        const int lane2 = s & 63, f = (s >> 6) & 3, cil = (s >> 8) & 3, hl = s >> 10;
        const int col2  = lane2 & 15, quad2 = lane2 >> 4;
        short8 d;
        if (isK) {   // K frag f=nb*2+half: K[2*col2+nb][half*32+quad2*8 ..+8]
            const int nb = f >> 1, half = f & 1;
            d = *(const short8*)&T[(cil * 32 + 2 * col2 + nb) * 136
                                   + hl * 64 + half * 32 + quad2 * 8];
        } else {     // V frag f=db: V[quad2*8+j'][db*16+col2] via transposed T
            d = *(const short8*)&T[(hl * 64 + f * 16 + col2) * 136
                                   + cil * 32 + quad2 * 8];
        }
        const int bh = bb * 16 + h0 + hl;
        const int ci = (k0t >> 5) + cil;
        const int fr = isK ? f : 4 + f;
        *(short8*)(kvp + (((size_t)bh * 64 + ci) * 8 + fr) * 512 + lane2 * 8) = d;
    }
}

// ---------------- MFMA bf16 GEMM: C = A @ Bt^T + bias -----------------------
// ROUND-12 VERBATIM: GK=32 + granule-XOR swizzle + XCD-chunked blockIdx.
// gemm3 at 128x64 -> 512 blocks = 2/CU.
template <typename OutT, int GM, int GN>
__global__ __launch_bounds__(256) void gemm_mfma_kernel(
    const short* __restrict__ A, const short* __restrict__ Bt,
    const float* __restrict__ bias, OutT* __restrict__ C,
    int M, int N, int Kd)
{
    constexpr int WM = GM / 2, WN = GN / 2;      // per-wave quadrant
    __shared__ __attribute__((aligned(16))) short As[GM * GK];
    __shared__ __attribute__((aligned(16))) short Bs[GN * GK];
    const int tid  = threadIdx.x;
    const int lane = tid & 63, w = tid >> 6;
    const int col  = lane & 15, quad = lane >> 4;
    const int wm = (w & 1) * WM, wn = (w >> 1) * WN;

    const int nwg  = gridDim.x * gridDim.y;
    const int bid0 = blockIdx.y * gridDim.x + blockIdx.x;
    const int bid  = (bid0 & 7) * (nwg >> 3) + (bid0 >> 3);
    const int row0 = (bid / gridDim.x) * GM, col0 = (bid % gridDim.x) * GN;

    const int sr  = tid >> 2;
    const int sxg = ((tid & 3) ^ ((sr >> 1) & 3)) * 8;
    const short* gA = A  + (size_t)(row0 + sr) * Kd + sxg;
    const short* gB = Bt + (size_t)(col0 + sr) * Kd + sxg;
    short* lA = As + tid * 8;
    short* lB = Bs + tid * 8;
    const size_t skip = (size_t)64 * Kd;

    const int xr8 = (quad ^ ((col >> 1) & 3)) * 8;   // swizzled read offset

    f32x4 acc[WM / 16][WN / 16] = {};
    for (int k0 = 0; k0 < Kd; k0 += GK) {
        __syncthreads();
        #pragma unroll
        for (int t = 0; t < GM / 64; ++t) GLL16(gA + t * skip, lA + t * 64 * GK);
        #pragma unroll
        for (int t = 0; t < GN / 64; ++t) GLL16(gB + t * skip, lB + t * 64 * GK);
        gA += GK; gB += GK;
        __syncthreads();

        short8 aF[WM / 16], bF[WN / 16];
        #pragma unroll
        for (int mt = 0; mt < WM / 16; ++mt)
            aF[mt] = *(const short8*)&As[(wm + mt * 16 + col) * GK + xr8];
        #pragma unroll
        for (int nt = 0; nt < WN / 16; ++nt)
            bF[nt] = *(const short8*)&Bs[(wn + nt * 16 + col) * GK + xr8];
        #pragma unroll
        for (int mt = 0; mt < WM / 16; ++mt)
            #pragma unroll
            for (int nt = 0; nt < WN / 16; ++nt)
                acc[mt][nt] = __builtin_amdgcn_mfma_f32_16x16x32_bf16(aF[mt], bF[nt], acc[mt][nt], 0, 0, 0);
    }

    #pragma unroll
    for (int mt = 0; mt < WM / 16; ++mt)
        #pragma unroll
        for (int i = 0; i < 4; ++i) {
            const size_t r = row0 + wm + mt * 16 + quad * 4 + i;
            #pragma unroll
            for (int nt = 0; nt < WN / 16; ++nt) {
                const int c = col0 + wn + nt * 16 + col;
                store_out(&C[r * N + c], acc[mt][nt][i] + bias[c]);
            }
        }
}

// ---------------- MFMA flash attention — batched P round-trip ----------------
// Round-13: the ONE flash lever never isolated (r7 bundled it with the
// demotion-causing lambda K-prefetch). r8-verbatim runs two sequential per-qg
// chains per chunk, each paying the P ds_write->ds_read RAW wait (~140cy).
// LDS ops are in-order per wave, so phase-restructuring the body:
//   S(qg0)+S(qg1) -> exp/mask both -> ALL 8 P-writes -> both P-reads -> PVs
// exposes ONE RAW window (~175cy) instead of two (~280cy), and issues all 8
// S-MFMAs back-to-back. No loop-carried aggregates, no out-ref lambdas, no
// conditional redefinition -- the r6/r7/r9 demotion triggers are absent.
// Cost: Sg[2][2] live (+8 VGPR) -> ~128 total (= 4 waves/SIMD boundary).
// Demotion tell: VGPR <= 64 or WRITE_SIZE >> 8MB -> revert to r8 form.
// Structure otherwise r8-verbatim: 32-q tiles, 2 qg/wave, 1024 blocks = 4/CU,
// pair-balanced (g, 63-g), pairwise cross-wave reduction, LDS 17.4KB.
#define DH 64

__global__ __launch_bounds__(256, 4) void flash_mfma_kernel(
    const short* __restrict__ qb,     // bf16 [B*K][C] Q only (pre-scaled)
    const short* __restrict__ kvp,    // fragment-packed K/V
    short* __restrict__ y,            // bf16 [B,K,C]
    int K, int C)
{
    // Or region (2 x 32 x 68 f32 = 17408B) aliases the P region (5120 sh):
    // P is live only during the chunk loop, Or only after the __syncthreads().
    __shared__ __attribute__((aligned(16))) short smem[8704];

    const int tid  = threadIdx.x;
    const int lane = tid & 63, w = tid >> 6;
    const int col  = lane & 15, quad = lane >> 4;

    short* Pw = smem + w * 1280;           // 2 qg bufs x 640 sh, wave-private

    const int cmb = blockIdx.x & 31;       // b*16+h  (XCD-local: idx%8 tracks h)
    const int g   = blockIdx.x >> 5;       // pair index 0..31
    const int b   = cmb >> 4, h = cmb & 15;

    short8 bOnes;                          // L = P @ ones-column = rowsum
    #pragma unroll
    for (int j = 0; j < 8; ++j) bOnes[j] = (col == 0) ? (short)0x3F80 : (short)0;

    const short* qbase  = qb + (size_t)b * K * C + h * DH;
    const short* kvbase = kvp + (size_t)cmb * 64 * 4096 + lane * 8;

    struct Frag { short8 k[2][2]; short8 v[4]; };
    auto loadF = [&](Frag& f, int ci) {
        const short* p = kvbase + (size_t)ci * 4096;
        f.k[0][0] = *(const short8*)(p);
        f.k[0][1] = *(const short8*)(p + 512);
        f.k[1][0] = *(const short8*)(p + 1024);
        f.k[1][1] = *(const short8*)(p + 1536);
        f.v[0]    = *(const short8*)(p + 2048);
        f.v[1]    = *(const short8*)(p + 2560);
        f.v[2]    = *(const short8*)(p + 3072);
        f.v[3]    = *(const short8*)(p + 3584);
    };

    auto run = [&](int T) {
        const int t0 = T * 32;
        const int NC = T + 1;              // 32-key chunks in this tile

        short8 aQ[2][2];
        #pragma unroll
        for (int qg = 0; qg < 2; ++qg) {
            const short* qp = qbase + (size_t)(t0 + qg * 16 + col) * C;
            aQ[qg][0] = *(const short8*)(qp + quad * 8);
            aQ[qg][1] = *(const short8*)(qp + 32 + quad * 8);
        }
        f32x4 O[2][4] = {};
        f32x4 L4[2] = {};

        for (int ci = w; ci < NC; ci += 4) {
            Frag f;
            loadF(f, ci);
            const int kc = ci * 32;
            __builtin_amdgcn_s_setprio(1);

            // ---- phase A: S-MFMAs for BOTH qg (8 back-to-back) ----
            f32x4 Sg[2][2] = {};
            #pragma unroll
            for (int qg = 0; qg < 2; ++qg)
                #pragma unroll
                for (int nb = 0; nb < 2; ++nb) {
                    Sg[qg][nb] = __builtin_amdgcn_mfma_f32_16x16x32_bf16(aQ[qg][0], f.k[nb][0], Sg[qg][nb], 0, 0, 0);
                    Sg[qg][nb] = __builtin_amdgcn_mfma_f32_16x16x32_bf16(aQ[qg][1], f.k[nb][1], Sg[qg][nb], 0, 0, 0);
                }

            // ---- phase B: exp/mask + P-writes for BOTH qg (8 writes) ----
            #pragma unroll
            for (int qg = 0; qg < 2; ++qg) {
                const int qb2 = t0 + qg * 16;
                short* Ptq = Pw + qg * 640;            // private per (wave,qg)
                if (kc + 31 <= qb2) {       // fully unmasked for this q-group
                    #pragma unroll
                    for (int i = 0; i < 4; ++i)
                        *(int*)&Ptq[(quad * 4 + i) * 40 + col * 2] =
                            pack2bf(EXP2(Sg[qg][0][i]), EXP2(Sg[qg][1][i]));
                } else {
                    const int kg = kc + col * 2;
                    #pragma unroll
                    for (int i = 0; i < 4; ++i) {
                        const int q = qb2 + quad * 4 + i;
                        float s0 = (kg + 0 <= q) ? Sg[qg][0][i] : -INFINITY;
                        float s1 = (kg + 1 <= q) ? Sg[qg][1][i] : -INFINITY;
                        *(int*)&Ptq[(quad * 4 + i) * 40 + col * 2] =
                            pack2bf(EXP2(s0), EXP2(s1));
                    }
                }
            }

            // ---- phase C: both P-reads (ONE exposed RAW window) ----
            short8 aP0 = *(const short8*)&Pw[col * 40 + quad * 8];
            short8 aP1 = *(const short8*)&Pw[640 + col * 40 + quad * 8];

            // ---- phase D: PVs + rowsums for both qg ----
            #pragma unroll
            for (int db = 0; db < 4; ++db) {
                O[0][db] = __builtin_amdgcn_mfma_f32_16x16x32_bf16(aP0, f.v[db], O[0][db], 0, 0, 0);
                O[1][db] = __builtin_amdgcn_mfma_f32_16x16x32_bf16(aP1, f.v[db], O[1][db], 0, 0, 0);
            }
            L4[0] = __builtin_amdgcn_mfma_f32_16x16x32_bf16(aP0, bOnes, L4[0], 0, 0, 0);
            L4[1] = __builtin_amdgcn_mfma_f32_16x16x32_bf16(aP1, bOnes, L4[1], 0, 0, 0);
            __builtin_amdgcn_s_setprio(0);
        }

        // ---- pairwise cross-wave reduction: w0->A, w1->B; w2+=A, w3+=B ----
        float* OrA = (float*)smem;               // 32 x 68 f32
        float* OrB = OrA + 32 * 68;
        __syncthreads();
        if (w < 2) {
            float* R = (w == 0) ? OrA : OrB;
            #pragma unroll
            for (int qg = 0; qg < 2; ++qg)
                #pragma unroll
                for (int i = 0; i < 4; ++i) {
                    const int row = qg * 16 + quad * 4 + i;
                    #pragma unroll
                    for (int db = 0; db < 4; ++db)
                        R[row * 68 + db * 16 + col] = O[qg][db][i];
                    if (col == 0) R[row * 68 + 64] = L4[qg][i];
                }
        }
        __syncthreads();
        if (w >= 2) {
            float* R = (w == 2) ? OrA : OrB;
            #pragma unroll
            for (int qg = 0; qg < 2; ++qg)
                #pragma unroll
                for (int i = 0; i < 4; ++i) {
                    const int row = qg * 16 + quad * 4 + i;
                    #pragma unroll
                    for (int db = 0; db < 4; ++db)
                        R[row * 68 + db * 16 + col] += O[qg][db][i];
                    if (col == 0) R[row * 68 + 64] += L4[qg][i];
                }
        }
        __syncthreads();

        // ---- combine A+B, normalize, store: wave w -> rows [w*8, w*8+8) ----
        #pragma unroll
        for (int rstep = 0; rstep < 2; ++rstep) {
            const int row = w * 8 + rstep * 4 + quad;
            f32x4 oa = *(const f32x4*)&OrA[row * 68 + col * 4];
            f32x4 ob = *(const f32x4*)&OrB[row * 68 + col * 4];
            const float inv = 1.f / (OrA[row * 68 + 64] + OrB[row * 68 + 64]);
            int2v o2 = { pack2bf((oa[0] + ob[0]) * inv, (oa[1] + ob[1]) * inv),
                         pack2bf((oa[2] + ob[2]) * inv, (oa[3] + ob[3]) * inv) };
            *(int2v*)(y + ((size_t)b * K + t0 + row) * C + h * DH + col * 4) = o2;
        }
        __syncthreads();   // protect Or/P alias before next tile restages
    };

    run(g);
    run(63 - g);
}

// ------------------------------- launch -------------------------------------
extern "C" void kernel_launch(void* const* d_in, const int* in_sizes, int n_in,
                              void* d_out, int out_size, void* d_ws, size_t ws_size,
                              hipStream_t stream)
{
    const float* x      = (const float*)d_in[0];
    const float* W_qkv  = (const float*)d_in[1];
    const float* b_qkv  = (const float*)d_in[2];
    const float* W_proj = (const float*)d_in[3];
    const float* b_proj = (const float*)d_in[4];

    const int B = 2, K = 2048, C = 1024, H = 16;
    const int M = B * K;   // 4096
    const float C2 = 0.18033688f;   // (1/sqrt(64)) * log2(e)

    char* ws = (char*)d_ws;
    short* xb    = (short*)ws;  ws += (size_t)M * C * 2;
    short* Wt1   = (short*)ws;  ws += (size_t)3 * C * C * 2;
    short* Wt2   = (short*)ws;  ws += (size_t)C * C * 2;
    short* qb    = (short*)ws;  ws += (size_t)M * C * 2;
    short* yb    = (short*)ws;  ws += (size_t)M * C * 2;
    short* kvp   = (short*)ws;  // 32 bh x 64 ci x 8 frag x 512 sh = 16.8 MB

    // prep (fused): cast x + transpose both weights
    const int nbx = (M * C) / 1024;
    const int nb1 = (3 * C / 32) * (C / 32);
    const int nb2 = (C / 32) * (C / 32);
    prep_kernel<<<nbx + nb1 + nb2, 256, 0, stream>>>(x, xb, M * C, W_qkv, Wt1, W_proj, Wt2, C);

    // 1) fused qkv GEMM: Q -> qb (pre-scaled), K/V -> kvp (fragment-packed)
    //    768 blocks = 3 blocks/CU; XCD-swizzled; GK=32 + granule-XOR swizzle
    dim3 g1((3 * C) / 128, M / 128);
    gemm_qkv_kernel<<<g1, 256, 0, stream>>>(xb, Wt1, b_qkv, qb, kvp, M, 3 * C, C, C, K, C2);

    // 2) flash attention -> yb (bf16); 1-D grid: idx = pair*32 + (b*16+h)
    //    32 pair-balanced 32-q tile-pairs x 32 bh = 1024 blocks (4/CU exact)
    flash_mfma_kernel<<<dim3(32 * 32), 256, 0, stream>>>(qb, kvp, yb, K, C);

    // 3) out = y @ W_proj + b_proj (fp32 out); 128x64 tile: 512 blocks = 2/CU
    dim3 g3(C / 64, M / 128);
    gemm_mfma_kernel<float, 128, 64><<<g3, 256, 0, stream>>>(yb, Wt2, b_proj, (float*)d_out, M, C, C);
}